// Round 9
// baseline (279.685 us; speedup 1.0000x reference)
//
#include <hip/hip_runtime.h>
#include <math.h>

// Pin FP contraction OFF for the whole file (r8-proven): every a*b+c stays
// rounded mul + rounded add. Explicit fma builtins unaffected (exact +-1 use).
#pragma clang fp contract(off)

#define EPSF 1e-10f
#define INV128 0.0078125f
#define C128 0.08838834764831845f   // np.float32(1/sqrt(128))

typedef float f2 __attribute__((ext_vector_type(2)));

__device__ __forceinline__ f2 fma2(f2 a, f2 b, f2 c) {
#if __has_builtin(__builtin_elementwise_fma)
    return __builtin_elementwise_fma(a, b, c);
#else
    f2 r; r.x = fmaf(a.x, b.x, c.x); r.y = fmaf(a.y, b.y, c.y); return r;
#endif
}

// ---------------- cross-lane primitives ------------------------------------

template<int CTRL>
__device__ __forceinline__ float fdpp(float v) {
    return __builtin_bit_cast(float,
        __builtin_amdgcn_update_dpp(0, __builtin_bit_cast(int, v), CTRL, 0xF, 0xF, true));
}
template<int PAT>
__device__ __forceinline__ float fswz(float v) {
    return __builtin_bit_cast(float,
        __builtin_amdgcn_ds_swizzle(__builtin_bit_cast(int, v), PAT));
}
// xor4 as pure DPP: banks 0,2 take row_ror:4; banks 1,3 take row_ror:12.
__device__ __forceinline__ float dpp_xor4(float v) {
    const int x = __builtin_bit_cast(int, v);
    int t = __builtin_amdgcn_update_dpp(x, x, 0x124, 0xF, 0x5, false);  // ror:4, banks 0,2
    t = __builtin_amdgcn_update_dpp(t, x, 0x12C, 0xF, 0xA, false);      // ror:12, banks 1,3
    return __builtin_bit_cast(float, t);
}
__device__ __forceinline__ float pl16(float v, bool low16) {
#if __has_builtin(__builtin_amdgcn_permlane16_swap)
    auto r = __builtin_amdgcn_permlane16_swap(
        __builtin_bit_cast(unsigned, v), __builtin_bit_cast(unsigned, v), false, false);
    return __builtin_bit_cast(float, low16 ? r[1] : r[0]);
#else
    return fswz<0x401F>(v);
#endif
}
__device__ __forceinline__ float pl32(float v, bool low32) {
#if __has_builtin(__builtin_amdgcn_permlane32_swap)
    auto r = __builtin_amdgcn_permlane32_swap(
        __builtin_bit_cast(unsigned, v), __builtin_bit_cast(unsigned, v), false, false);
    return __builtin_bit_cast(float, low32 ? r[1] : r[0]);
#else
    return __shfl_xor(v, 32, 64);
#endif
}

struct LaneB { bool low16, low32; };

// MODE 0: all __shfl_xor (always-correct fallback)
// MODE 1: r8-proven mix (DPP xor1/2/8, ds_swizzle xor4/16, permlane xor32)
// MODE 2: LDS-free (DPP xor1/2/4/8, permlane16 xor16, permlane32 xor32)
template<int MODE, int D>
__device__ __forceinline__ float partner(float v, const LaneB& L) {
    if constexpr (MODE == 0)   { return __shfl_xor(v, D, 64); }
    else if constexpr (D == 1) { return fdpp<0xB1>(v); }
    else if constexpr (D == 2) { return fdpp<0x4E>(v); }
    else if constexpr (D == 4) { if constexpr (MODE == 2) return dpp_xor4(v);
                                 else return fswz<0x101F>(v); }
    else if constexpr (D == 8) { return fdpp<0x128>(v); }
    else if constexpr (D == 16){ if constexpr (MODE == 2) return pl16(v, L.low16);
                                 else return fswz<0x401F>(v); }
    else                       { return pl32(v, L.low32); }
}
template<int MODE, int D>
__device__ __forceinline__ f2 partner2(f2 v, const LaneB& L) {
    f2 r; r.x = partner<MODE, D>(v.x, L); r.y = partner<MODE, D>(v.y, L);
    return r;
}

// dual-row wave reduction (two independent chains interleaved for ILP)
template<int MODE>
__device__ __forceinline__ void wsum2(float& a, float& b, const LaneB& L) {
    a += partner<MODE, 1>(a, L);  b += partner<MODE, 1>(b, L);
    a += partner<MODE, 2>(a, L);  b += partner<MODE, 2>(b, L);
    a += partner<MODE, 4>(a, L);  b += partner<MODE, 4>(b, L);
    a += partner<MODE, 8>(a, L);  b += partner<MODE, 8>(b, L);
    a += partner<MODE, 16>(a, L); b += partner<MODE, 16>(b, L);
    a += partner<MODE, 32>(a, L); b += partner<MODE, 32>(b, L);
}

struct SignsP { f2 s[6]; };

// dual-row FWHT-128; lane l holds (e[2l], e[2l+1]) of each row.
// fma2 with s=+-1 is bitwise identical to add/sub.
template<int MODE, bool SCALE>
__device__ __forceinline__ void fwht128x2(f2& u, f2& w, const SignsP& S, const LaneB& L) {
    { f2 t; t.x = u.x + u.y; t.y = u.x - u.y; u = t; }
    { f2 t; t.x = w.x + w.y; t.y = w.x - w.y; w = t; }
#define STG(D, K) { f2 pu = partner2<MODE, D>(u, L); f2 pw = partner2<MODE, D>(w, L); \
                    u = fma2(S.s[K], u, pu); w = fma2(S.s[K], w, pw); }
    STG(1, 0) STG(2, 1) STG(4, 2) STG(8, 3) STG(16, 4) STG(32, 5)
#undef STG
    if constexpr (SCALE) { u = u * C128; w = w * C128; }
}

// Self-checks: bitwise vs __shfl_xor on a distinguishing pattern; wave-uniform.
__device__ __forceinline__ bool mode1_ok(int lane, const LaneB& L) {
    const float tv = __int_as_float(0x3f800000 + lane * 1024);
    bool ok = true;
    ok = ok && (__float_as_uint(partner<1, 1>(tv, L))  == __float_as_uint(__shfl_xor(tv, 1, 64)));
    ok = ok && (__float_as_uint(partner<1, 2>(tv, L))  == __float_as_uint(__shfl_xor(tv, 2, 64)));
    ok = ok && (__float_as_uint(partner<1, 4>(tv, L))  == __float_as_uint(__shfl_xor(tv, 4, 64)));
    ok = ok && (__float_as_uint(partner<1, 8>(tv, L))  == __float_as_uint(__shfl_xor(tv, 8, 64)));
    ok = ok && (__float_as_uint(partner<1, 16>(tv, L)) == __float_as_uint(__shfl_xor(tv, 16, 64)));
    ok = ok && (__float_as_uint(partner<1, 32>(tv, L)) == __float_as_uint(__shfl_xor(tv, 32, 64)));
    return __all((int)ok) != 0;
}
__device__ __forceinline__ bool mode2_ok(int lane, const LaneB& L) {
    const float tv = __int_as_float(0x3f800000 + lane * 1024);
    bool ok = true;
    ok = ok && (__float_as_uint(dpp_xor4(tv))     == __float_as_uint(__shfl_xor(tv, 4, 64)));
    ok = ok && (__float_as_uint(pl16(tv, L.low16)) == __float_as_uint(__shfl_xor(tv, 16, 64)));
    return __all((int)ok) != 0;
}

// ---------------------------------------------------------------------------
// Setup: PROVEN r8 128-thread Lloyd-Max (f64 shared, token-identical formulas)
// + direct-cell table build.
// ws layout (floats): [1792..5887] float4 tbl4[1024]{bnd[g],cb[g],cb[g+1],0}
// where g = #bounds < cell_left, cell c covers [-4 + c/128, -4 + (c+1)/128).
// ---------------------------------------------------------------------------
__global__ __launch_bounds__(128) void lloyd_setup_kernel(float* __restrict__ ws) {
    __shared__ double lv[128];
    __shared__ double bp[127];
    __shared__ double bc[127];
    __shared__ float scb[128];
    __shared__ float sbnd[128];

    const int i = threadIdx.x;   // 0..127
    lv[i] = (i == 127) ? 4.0 : (-4.0 + (8.0 / 127.0) * (double)i);
    __syncthreads();

    const double inv_sqrt2pi = 0.39894228040143267794;
    const double inv_sqrt2   = 0.70710678118654752440;
    const double pdf_end = exp(-0.5 * 30.0 * 30.0) * inv_sqrt2pi;
    const double cdf_m30 = 0.5 * (1.0 + erf(-30.0 * inv_sqrt2));
    const double cdf_p30 = 0.5 * (1.0 + erf( 30.0 * inv_sqrt2));

    for (int it = 0; it < 200; ++it) {
        if (i < 127) {
            double t = 0.5 * (lv[i] + lv[i + 1]);
            t = fmin(fmax(t, -30.0), 30.0);
            bp[i] = exp(-0.5 * t * t) * inv_sqrt2pi;
            bc[i] = 0.5 * (1.0 + erf(t * inv_sqrt2));
        }
        __syncthreads();
        const double plo = (i == 0)   ? pdf_end : bp[i - 1];
        const double clo = (i == 0)   ? cdf_m30 : bc[i - 1];
        const double phi = (i == 127) ? pdf_end : bp[i];
        const double chi = (i == 127) ? cdf_p30 : bc[i];
        const double nl  = (plo - phi) / fmax(chi - clo, 1e-30);
        __syncthreads();
        lv[i] = nl;
        __syncthreads();
    }

    const float cf = (float)lv[i];
    scb[i] = cf;
    __syncthreads();

    const float INF = __int_as_float(0x7f800000);
    const float nb = (i < 127) ? 0.5f * (scb[i] + scb[i + 1]) : INF;
    sbnd[i] = nb;
    __syncthreads();

    // direct cell table: one ds_read_b128 replaces the lut->tbl gather chain
    float4* t4 = (float4*)(ws + 1792);
    for (int c = i; c < 1024; c += 128) {
        const float cl = -4.0f + (float)c * 0.0078125f;   // cell left edge
        int g = 0;
#pragma unroll
        for (int d = 64; d >= 1; d >>= 1) g += (sbnd[g + d - 1] < cl) ? d : 0;
        // at most one boundary inside any 1/128-wide cell (min gap ~0.034)
        t4[c] = make_float4(sbnd[g], scb[g], scb[(g < 127) ? g + 1 : 127], 0.0f);
    }
}

// ---------------------------------------------------------------------------
// Main kernel: one wave per row-pair (row, row+half) — dual-chain ILP.
// ---------------------------------------------------------------------------
__device__ __forceinline__ float lm_recon(const float4* __restrict__ tbl4, float v) {
    float cf = fminf(fmaxf(fmaf(v, 128.0f, 512.0f), 0.0f), 1023.0f);
    const float4 e = tbl4[(int)cf];
    return (e.x < v) ? e.z : e.y;   // searchsorted side='left'
}

template<int MODE>
__device__ __forceinline__ void run2(
        const float* __restrict__ x, float* __restrict__ out,
        const float4* __restrict__ tbl4,
        f2 rs0, f2 rs1, f2 qj,
        const SignsP S, const LaneB L, int lane, int row0, int wstride, int half) {
    for (int row = row0; row < half; row += wstride) {
        const float2 xa = ((const float2*)(x + (size_t)row * 128))[lane];
        const float2 xb = ((const float2*)(x + (size_t)(row + half) * 128))[lane];
        f2 u; u.x = xa.x; u.y = xa.y;
        f2 w; w.x = xb.x; w.y = xb.y;

        // ---- norms, unit vectors ----
        float su = u.x * u.x + u.y * u.y;
        float sw = w.x * w.x + w.y * w.y;
        wsum2<MODE>(su, sw, L);
        const float nu = sqrtf(su), nw = sqrtf(sw);
        const float iu = 1.0f / (nu + EPSF), iw = 1.0f / (nw + EPSF);
        u = u * iu; w = w * iw;

        // ---- rotation_fwd, per-FWHT normalized (feeds quantizer) ----
        u = u * rs0; w = w * rs0;
        fwht128x2<MODE, true>(u, w, S, L);
        u = u * rs1; w = w * rs1;
        fwht128x2<MODE, true>(u, w, S, L);

        // ---- pass 1: numerical rms + LM quantize ----
        float r2u = u.x * u.x + u.y * u.y;
        float r2w = w.x * w.x + w.y * w.y;
        wsum2<MODE>(r2u, r2w, L);
        const float rmsu = sqrtf(r2u) * C128;
        const float rmsw = sqrtf(r2w) * C128;
        const float siu = 1.0f / (rmsu + EPSF);
        const float siw = 1.0f / (rmsw + EPSF);
        f2 ru, rw;
        ru.x = lm_recon(tbl4, u.x * siu); ru.y = lm_recon(tbl4, u.y * siu);
        rw.x = lm_recon(tbl4, w.x * siw); rw.y = lm_recon(tbl4, w.y * siw);

        // ---- refined gamma ----
        float numu = u.x * ru.x + u.y * ru.y;
        float numw = w.x * rw.x + w.y * rw.y;
        float denu = ru.x * ru.x + ru.y * ru.y;
        float denw = rw.x * rw.x + rw.y * rw.y;
        wsum2<MODE>(numu, numw, L);
        wsum2<MODE>(denu, denw, L);
        const float gu = numu / (denu + EPSF), gw = numw / (denw + EPSF);
        const float giu = 1.0f / (gu + EPSF), giw = 1.0f / (gw + EPSF);

        // ---- MSE-stage quantize ----
        f2 qu, qw;
        qu.x = lm_recon(tbl4, u.x * giu); qu.y = lm_recon(tbl4, u.y * giu);
        qw.x = lm_recon(tbl4, w.x * giw); qw.y = lm_recon(tbl4, w.y * giw);
        const f2 rcu = qu * gu, rcw = qw * gw;   // rounded mul
        const f2 reu = u - rcu, rew = w - rcw;   // rounded sub
        float rnu = reu.x * reu.x + reu.y * reu.y;
        float rnw = rew.x * rew.x + rew.y * rew.y;
        wsum2<MODE>(rnu, rnw, L);
        const float resnu = sqrtf(rnu), resnw = sqrtf(rnw);

        // ==== post-quantization (ulp-safe folds) ====
        f2 pu = reu * qj, pw = rew * qj;
        fwht128x2<MODE, false>(pu, pw, S, L);
        f2 sgu, sgw;
        sgu.x = (pu.x >= 0.0f) ? 1.0f : -1.0f; sgu.y = (pu.y >= 0.0f) ? 1.0f : -1.0f;
        sgw.x = (pw.x >= 0.0f) ? 1.0f : -1.0f; sgw.y = (pw.y >= 0.0f) ? 1.0f : -1.0f;
        fwht128x2<MODE, false>(sgu, sgw, S, L);  // exact integers
        const float rsu = resnu * INV128, rsw = resnw * INV128;
        f2 cu, cw;
        cu.x = fmaf(sgu.x * qj.x, rsu, rcu.x); cu.y = fmaf(sgu.y * qj.y, rsu, rcu.y);
        cw.x = fmaf(sgw.x * qj.x, rsw, rcw.x); cw.y = fmaf(sgw.y * qj.y, rsw, rcw.y);

        // ---- inverse rotation (folded scales) ----
        fwht128x2<MODE, false>(cu, cw, S, L);
        cu = cu * rs1; cw = cw * rs1;
        fwht128x2<MODE, false>(cu, cw, S, L);
        const float fnu = nu * INV128, fnw = nw * INV128;
        cu = cu * rs0; cw = cw * rs0;
        cu = cu * fnu; cw = cw * fnw;
        float2 ou; ou.x = cu.x; ou.y = cu.y;
        float2 ov; ov.x = cw.x; ov.y = cw.y;
        ((float2*)(out + (size_t)row * 128))[lane] = ou;
        ((float2*)(out + (size_t)(row + half) * 128))[lane] = ov;
    }
}

__global__ __launch_bounds__(256) void turboquant_kernel(
        const float* __restrict__ x,
        const float* __restrict__ rot,
        const float* __restrict__ qjl,
        const float* __restrict__ ws,
        float* __restrict__ out,
        const int nrows) {
    __shared__ float4 tbl4[1024];
    const int t = threadIdx.x;
    {
        const float4* src = (const float4*)(ws + 1792);
#pragma unroll
        for (int i = 0; i < 4; ++i) tbl4[t + 256 * i] = src[t + 256 * i];
    }
    __syncthreads();

    const int lane = t & 63;
    const int wid  = t >> 6;
    LaneB L; L.low16 = (lane & 16) == 0; L.low32 = (lane & 32) == 0;

    SignsP S;
#pragma unroll
    for (int k = 0; k < 6; ++k) {
        const float s = (lane & (1 << k)) ? -1.0f : 1.0f;
        S.s[k].x = s; S.s[k].y = s;
    }

    const float2 r0 = ((const float2*)rot)[lane];
    const float2 r1 = ((const float2*)rot)[64 + lane];
    const float2 qq = ((const float2*)qjl)[lane];
    f2 rs0; rs0.x = r0.x; rs0.y = r0.y;
    f2 rs1; rs1.x = r1.x; rs1.y = r1.y;
    f2 qj;  qj.x  = qq.x; qj.y  = qq.y;

    const int half    = nrows >> 1;
    const int row0    = blockIdx.x * 4 + wid;
    const int wstride = gridDim.x * 4;

    const bool m1 = mode1_ok(lane, L);
    const bool m2 = m1 && mode2_ok(lane, L);
    if (m2)
        run2<2>(x, out, tbl4, rs0, rs1, qj, S, L, lane, row0, wstride, half);
    else if (m1)
        run2<1>(x, out, tbl4, rs0, rs1, qj, S, L, lane, row0, wstride, half);
    else
        run2<0>(x, out, tbl4, rs0, rs1, qj, S, L, lane, row0, wstride, half);
}

extern "C" void kernel_launch(void* const* d_in, const int* in_sizes, int n_in,
                              void* d_out, int out_size, void* d_ws, size_t ws_size,
                              hipStream_t stream) {
    const float* x   = (const float*)d_in[0];
    const float* rot = (const float*)d_in[1];
    const float* qjl = (const float*)d_in[2];
    float* out = (float*)d_out;
    float* ws  = (float*)d_ws;

    const int nrows = in_sizes[0] >> 7;

    lloyd_setup_kernel<<<1, 128, 0, stream>>>(ws);
    turboquant_kernel<<<8192, 256, 0, stream>>>(x, rot, qjl, ws, out, nrows);
}

// Round 10
// 270.330 us; speedup vs baseline: 1.0346x; 1.0346x over previous
//
#include <hip/hip_runtime.h>
#include <math.h>

// Pin FP contraction OFF (r8/r9-proven): every a*b+c stays rounded mul +
// rounded add. Explicit fma/pk_fma used only where exact (s = +-1).
#pragma clang fp contract(off)

#define EPSF 1e-10f
#define INV128 0.0078125f
#define C128 0.08838834764831845f   // np.float32(1/sqrt(128))

typedef float f2 __attribute__((ext_vector_type(2)));

// ---------------- packed f32 math (CDNA VOP3P; per-half IEEE) ---------------
__device__ __forceinline__ f2 pk_fma(f2 a, f2 b, f2 c) {
    f2 d;
    asm("v_pk_fma_f32 %0, %1, %2, %3" : "=v"(d) : "v"(a), "v"(b), "v"(c));
    return d;
}
__device__ __forceinline__ f2 pk_mul(f2 a, f2 b) {
    f2 d;
    asm("v_pk_mul_f32 %0, %1, %2" : "=v"(d) : "v"(a), "v"(b));
    return d;
}
__device__ __forceinline__ f2 pk_add(f2 a, f2 b) {
    f2 d;
    asm("v_pk_add_f32 %0, %1, %2" : "=v"(d) : "v"(a), "v"(b));
    return d;
}

// ---------------- cross-lane primitives ------------------------------------

template<int CTRL>
__device__ __forceinline__ float fdpp(float v) {
    return __builtin_bit_cast(float,
        __builtin_amdgcn_update_dpp(0, __builtin_bit_cast(int, v), CTRL, 0xF, 0xF, true));
}
template<int PAT>
__device__ __forceinline__ float fswz(float v) {
    return __builtin_bit_cast(float,
        __builtin_amdgcn_ds_swizzle(__builtin_bit_cast(int, v), PAT));
}
// xor4 as pure DPP: banks 0,2 take row_ror:4; banks 1,3 take row_ror:12.
__device__ __forceinline__ float dpp_xor4(float v) {
    const int x = __builtin_bit_cast(int, v);
    int t = __builtin_amdgcn_update_dpp(x, x, 0x124, 0xF, 0x5, false);  // ror:4, banks 0,2
    t = __builtin_amdgcn_update_dpp(t, x, 0x12C, 0xF, 0xA, false);      // ror:12, banks 1,3
    return __builtin_bit_cast(float, t);
}
__device__ __forceinline__ float pl16(float v, bool low16) {
#if __has_builtin(__builtin_amdgcn_permlane16_swap)
    auto r = __builtin_amdgcn_permlane16_swap(
        __builtin_bit_cast(unsigned, v), __builtin_bit_cast(unsigned, v), false, false);
    return __builtin_bit_cast(float, low16 ? r[1] : r[0]);
#else
    return fswz<0x401F>(v);
#endif
}
__device__ __forceinline__ float pl32(float v, bool low32) {
#if __has_builtin(__builtin_amdgcn_permlane32_swap)
    auto r = __builtin_amdgcn_permlane32_swap(
        __builtin_bit_cast(unsigned, v), __builtin_bit_cast(unsigned, v), false, false);
    return __builtin_bit_cast(float, low32 ? r[1] : r[0]);
#else
    return __shfl_xor(v, 32, 64);
#endif
}

struct LaneB { bool low16, low32; };

// MODE 0: all __shfl_xor | MODE 1: r8-proven mix | MODE 2: LDS-free (r9-proven)
template<int MODE, int D>
__device__ __forceinline__ float partner(float v, const LaneB& L) {
    if constexpr (MODE == 0)   { return __shfl_xor(v, D, 64); }
    else if constexpr (D == 1) { return fdpp<0xB1>(v); }
    else if constexpr (D == 2) { return fdpp<0x4E>(v); }
    else if constexpr (D == 4) { if constexpr (MODE == 2) return dpp_xor4(v);
                                 else return fswz<0x101F>(v); }
    else if constexpr (D == 8) { return fdpp<0x128>(v); }
    else if constexpr (D == 16){ if constexpr (MODE == 2) return pl16(v, L.low16);
                                 else return fswz<0x401F>(v); }
    else                       { return pl32(v, L.low32); }
}
template<int MODE, int D>
__device__ __forceinline__ f2 partner2(f2 v, const LaneB& L) {
    f2 r; r.x = partner<MODE, D>(v.x, L); r.y = partner<MODE, D>(v.y, L);
    return r;
}

// dual-row wave reduction: the two rows' partials packed into one f2;
// pk_add halves the add count. Per-half order identical to r9 (bitwise-same).
template<int MODE>
__device__ __forceinline__ void wsum2(float& a, float& b, const LaneB& L) {
    f2 p; p.x = a; p.y = b;
    p = pk_add(p, partner2<MODE, 1>(p, L));
    p = pk_add(p, partner2<MODE, 2>(p, L));
    p = pk_add(p, partner2<MODE, 4>(p, L));
    p = pk_add(p, partner2<MODE, 8>(p, L));
    p = pk_add(p, partner2<MODE, 16>(p, L));
    p = pk_add(p, partner2<MODE, 32>(p, L));
    a = p.x; b = p.y;
}

struct SignsP { f2 s[6]; };

// dual-row FWHT-128; lane l holds (e[2l], e[2l+1]) of each row.
// pk_fma with s=+-1 per half is bitwise identical to r9's scalar fma pair.
template<int MODE, bool SCALE>
__device__ __forceinline__ void fwht128x2(f2& u, f2& w, const SignsP& S, const LaneB& L) {
    { f2 t; t.x = u.x + u.y; t.y = u.x - u.y; u = t; }
    { f2 t; t.x = w.x + w.y; t.y = w.x - w.y; w = t; }
#define STG(D, K) { f2 pu = partner2<MODE, D>(u, L); f2 pw = partner2<MODE, D>(w, L); \
                    u = pk_fma(S.s[K], u, pu); w = pk_fma(S.s[K], w, pw); }
    STG(1, 0) STG(2, 1) STG(4, 2) STG(8, 3) STG(16, 4) STG(32, 5)
#undef STG
    if constexpr (SCALE) {
        f2 cc; cc.x = C128; cc.y = C128;
        u = pk_mul(u, cc); w = pk_mul(w, cc);
    }
}

// Self-checks: bitwise vs __shfl_xor on a distinguishing pattern; wave-uniform.
__device__ __forceinline__ bool mode1_ok(int lane, const LaneB& L) {
    const float tv = __int_as_float(0x3f800000 + lane * 1024);
    bool ok = true;
    ok = ok && (__float_as_uint(partner<1, 1>(tv, L))  == __float_as_uint(__shfl_xor(tv, 1, 64)));
    ok = ok && (__float_as_uint(partner<1, 2>(tv, L))  == __float_as_uint(__shfl_xor(tv, 2, 64)));
    ok = ok && (__float_as_uint(partner<1, 4>(tv, L))  == __float_as_uint(__shfl_xor(tv, 4, 64)));
    ok = ok && (__float_as_uint(partner<1, 8>(tv, L))  == __float_as_uint(__shfl_xor(tv, 8, 64)));
    ok = ok && (__float_as_uint(partner<1, 16>(tv, L)) == __float_as_uint(__shfl_xor(tv, 16, 64)));
    ok = ok && (__float_as_uint(partner<1, 32>(tv, L)) == __float_as_uint(__shfl_xor(tv, 32, 64)));
    return __all((int)ok) != 0;
}
__device__ __forceinline__ bool mode2_ok(int lane, const LaneB& L) {
    const float tv = __int_as_float(0x3f800000 + lane * 1024);
    bool ok = true;
    ok = ok && (__float_as_uint(dpp_xor4(tv))      == __float_as_uint(__shfl_xor(tv, 4, 64)));
    ok = ok && (__float_as_uint(pl16(tv, L.low16)) == __float_as_uint(__shfl_xor(tv, 16, 64)));
    // pk sanity: per-half semantics on asymmetric halves
    f2 ta; ta.x = 3.0f; ta.y = 5.0f;
    f2 tb; tb.x = 7.0f; tb.y = 11.0f;
    f2 tc; tc.x = 13.0f; tc.y = 17.0f;
    f2 rf = pk_fma(ta, tb, tc);
    f2 rm = pk_mul(ta, tb);
    f2 rs = pk_add(ta, tb);
    ok = ok && (rf.x == 34.0f) && (rf.y == 72.0f);
    ok = ok && (rm.x == 21.0f) && (rm.y == 55.0f);
    ok = ok && (rs.x == 10.0f) && (rs.y == 16.0f);
    return __all((int)ok) != 0;
}

// ---------------------------------------------------------------------------
// Setup: Lloyd-Max, token-identical f64 formulas (r9-proven), but lv held in
// registers; neighbor exchange via __shfl (r6-proven) + LDS handoff at the
// wave 63<->64 crossover. 2 barriers/iter instead of 3.
// ws layout (floats): [1792..5887] float4 tbl4[1024]{bnd[g],cb[g],cb[g+1],0}.
// ---------------------------------------------------------------------------
__global__ __launch_bounds__(128) void lloyd_setup_kernel(float* __restrict__ ws) {
    const int i = threadIdx.x;   // 0..127; thread i owns lv[i]
    __shared__ double xch[3];    // [0]=lv[64], [1]=bp[63], [2]=bc[63]
    __shared__ float scb[128];
    __shared__ float sbnd[128];

    double lv = (i == 127) ? 4.0 : (-4.0 + (8.0 / 127.0) * (double)i);

    const double inv_sqrt2pi = 0.39894228040143267794;
    const double inv_sqrt2   = 0.70710678118654752440;
    const double pdf_end = exp(-0.5 * 30.0 * 30.0) * inv_sqrt2pi;
    const double cdf_m30 = 0.5 * (1.0 + erf(-30.0 * inv_sqrt2));
    const double cdf_p30 = 0.5 * (1.0 + erf( 30.0 * inv_sqrt2));

#pragma unroll 1
    for (int it = 0; it < 200; ++it) {
        if (i == 64) xch[0] = lv;
        __syncthreads();
        double lvn = __shfl_down(lv, 1, 64);   // lv[i+1] within wave
        if (i == 63) lvn = xch[0];             // cross-wave: lv[64]
        double bp_ = 0.0, bc_ = 0.0;           // boundary i (i<127)
        if (i < 127) {
            double t = 0.5 * (lv + lvn);
            t = fmin(fmax(t, -30.0), 30.0);
            bp_ = exp(-0.5 * t * t) * inv_sqrt2pi;
            bc_ = 0.5 * (1.0 + erf(t * inv_sqrt2));
        }
        if (i == 63) { xch[1] = bp_; xch[2] = bc_; }
        __syncthreads();
        double plo = __shfl_up(bp_, 1, 64);    // bp[i-1] within wave
        double clo = __shfl_up(bc_, 1, 64);
        if (i == 64) { plo = xch[1]; clo = xch[2]; }   // cross-wave: bp/bc[63]
        if (i == 0)  { plo = pdf_end; clo = cdf_m30; }
        const double phi = (i == 127) ? pdf_end : bp_;
        const double chi = (i == 127) ? cdf_p30 : bc_;
        lv = (plo - phi) / fmax(chi - clo, 1e-30);
    }

    const float cf = (float)lv;
    scb[i] = cf;
    __syncthreads();
    const float INF = __int_as_float(0x7f800000);
    const float nb = (i < 127) ? 0.5f * (scb[i] + scb[i + 1]) : INF;
    sbnd[i] = nb;
    __syncthreads();

    // direct cell table (r9-proven): at most one boundary per 1/128-wide cell
    float4* t4 = (float4*)(ws + 1792);
    for (int c = i; c < 1024; c += 128) {
        const float cl = -4.0f + (float)c * 0.0078125f;
        int g = 0;
#pragma unroll
        for (int d = 64; d >= 1; d >>= 1) g += (sbnd[g + d - 1] < cl) ? d : 0;
        t4[c] = make_float4(sbnd[g], scb[g], scb[(g < 127) ? g + 1 : 127], 0.0f);
    }
}

// ---------------------------------------------------------------------------
// Main kernel: one wave per row-pair (row, row+half) — dual-chain + pk math.
// ---------------------------------------------------------------------------
__device__ __forceinline__ float lm_recon(const float4* __restrict__ tbl4, float v) {
    float cf = fminf(fmaxf(fmaf(v, 128.0f, 512.0f), 0.0f), 1023.0f);
    const float4 e = tbl4[(int)cf];
    return (e.x < v) ? e.z : e.y;   // searchsorted side='left'
}

template<int MODE>
__device__ __forceinline__ void run2(
        const float* __restrict__ x, float* __restrict__ out,
        const float4* __restrict__ tbl4,
        f2 rs0, f2 rs1, f2 qj,
        const SignsP S, const LaneB L, int lane, int row0, int wstride, int half) {
    for (int row = row0; row < half; row += wstride) {
        const float2 xa = ((const float2*)(x + (size_t)row * 128))[lane];
        const float2 xb = ((const float2*)(x + (size_t)(row + half) * 128))[lane];
        f2 u; u.x = xa.x; u.y = xa.y;
        f2 w; w.x = xb.x; w.y = xb.y;

        // ---- norms, unit vectors ----
        float su = u.x * u.x + u.y * u.y;
        float sw = w.x * w.x + w.y * w.y;
        wsum2<MODE>(su, sw, L);
        const float nu = sqrtf(su), nw = sqrtf(sw);
        const float iu = 1.0f / (nu + EPSF), iw = 1.0f / (nw + EPSF);
        f2 vu; vu.x = iu; vu.y = iu;
        f2 vw; vw.x = iw; vw.y = iw;
        u = pk_mul(u, vu); w = pk_mul(w, vw);

        // ---- rotation_fwd, per-FWHT normalized (feeds quantizer) ----
        u = pk_mul(u, rs0); w = pk_mul(w, rs0);
        fwht128x2<MODE, true>(u, w, S, L);
        u = pk_mul(u, rs1); w = pk_mul(w, rs1);
        fwht128x2<MODE, true>(u, w, S, L);

        // ---- pass 1: numerical rms + LM quantize ----
        float r2u = u.x * u.x + u.y * u.y;
        float r2w = w.x * w.x + w.y * w.y;
        wsum2<MODE>(r2u, r2w, L);
        const float rmsu = sqrtf(r2u) * C128;
        const float rmsw = sqrtf(r2w) * C128;
        const float siu = 1.0f / (rmsu + EPSF);
        const float siw = 1.0f / (rmsw + EPSF);
        f2 ru, rw;
        ru.x = lm_recon(tbl4, u.x * siu); ru.y = lm_recon(tbl4, u.y * siu);
        rw.x = lm_recon(tbl4, w.x * siw); rw.y = lm_recon(tbl4, w.y * siw);

        // ---- refined gamma ----
        float numu = u.x * ru.x + u.y * ru.y;
        float numw = w.x * rw.x + w.y * rw.y;
        float denu = ru.x * ru.x + ru.y * ru.y;
        float denw = rw.x * rw.x + rw.y * rw.y;
        wsum2<MODE>(numu, numw, L);
        wsum2<MODE>(denu, denw, L);
        const float gu = numu / (denu + EPSF), gw = numw / (denw + EPSF);
        const float giu = 1.0f / (gu + EPSF), giw = 1.0f / (gw + EPSF);

        // ---- MSE-stage quantize ----
        f2 qu, qw;
        qu.x = lm_recon(tbl4, u.x * giu); qu.y = lm_recon(tbl4, u.y * giu);
        qw.x = lm_recon(tbl4, w.x * giw); qw.y = lm_recon(tbl4, w.y * giw);
        f2 g2u; g2u.x = gu; g2u.y = gu;
        f2 g2w; g2w.x = gw; g2w.y = gw;
        const f2 rcu = pk_mul(qu, g2u), rcw = pk_mul(qw, g2w);  // rounded mul
        f2 reu, rew;                                            // rounded sub
        reu.x = u.x - rcu.x; reu.y = u.y - rcu.y;
        rew.x = w.x - rcw.x; rew.y = w.y - rcw.y;
        float rnu = reu.x * reu.x + reu.y * reu.y;
        float rnw = rew.x * rew.x + rew.y * rew.y;
        wsum2<MODE>(rnu, rnw, L);
        const float resnu = sqrtf(rnu), resnw = sqrtf(rnw);

        // ==== post-quantization (ulp-safe folds) ====
        f2 pu = pk_mul(reu, qj), pw = pk_mul(rew, qj);
        fwht128x2<MODE, false>(pu, pw, S, L);
        f2 sgu, sgw;
        sgu.x = (pu.x >= 0.0f) ? 1.0f : -1.0f; sgu.y = (pu.y >= 0.0f) ? 1.0f : -1.0f;
        sgw.x = (pw.x >= 0.0f) ? 1.0f : -1.0f; sgw.y = (pw.y >= 0.0f) ? 1.0f : -1.0f;
        fwht128x2<MODE, false>(sgu, sgw, S, L);  // exact integers
        const float rsu = resnu * INV128, rsw = resnw * INV128;
        f2 r2su; r2su.x = rsu; r2su.y = rsu;
        f2 r2sw; r2sw.x = rsw; r2sw.y = rsw;
        f2 cu = pk_fma(pk_mul(sgu, qj), r2su, rcu);
        f2 cw = pk_fma(pk_mul(sgw, qj), r2sw, rcw);

        // ---- inverse rotation (folded scales) ----
        fwht128x2<MODE, false>(cu, cw, S, L);
        cu = pk_mul(cu, rs1); cw = pk_mul(cw, rs1);
        fwht128x2<MODE, false>(cu, cw, S, L);
        const float fnu = nu * INV128, fnw = nw * INV128;
        f2 f2u; f2u.x = fnu; f2u.y = fnu;
        f2 f2w; f2w.x = fnw; f2w.y = fnw;
        cu = pk_mul(pk_mul(cu, rs0), f2u);
        cw = pk_mul(pk_mul(cw, rs0), f2w);
        float2 ou; ou.x = cu.x; ou.y = cu.y;
        float2 ov; ov.x = cw.x; ov.y = cw.y;
        ((float2*)(out + (size_t)row * 128))[lane] = ou;
        ((float2*)(out + (size_t)(row + half) * 128))[lane] = ov;
    }
}

__global__ __launch_bounds__(256) void turboquant_kernel(
        const float* __restrict__ x,
        const float* __restrict__ rot,
        const float* __restrict__ qjl,
        const float* __restrict__ ws,
        float* __restrict__ out,
        const int nrows) {
    __shared__ float4 tbl4[1024];
    const int t = threadIdx.x;
    {
        const float4* src = (const float4*)(ws + 1792);
#pragma unroll
        for (int i = 0; i < 4; ++i) tbl4[t + 256 * i] = src[t + 256 * i];
    }
    __syncthreads();

    const int lane = t & 63;
    const int wid  = t >> 6;
    LaneB L; L.low16 = (lane & 16) == 0; L.low32 = (lane & 32) == 0;

    SignsP S;
#pragma unroll
    for (int k = 0; k < 6; ++k) {
        const float s = (lane & (1 << k)) ? -1.0f : 1.0f;
        S.s[k].x = s; S.s[k].y = s;
    }

    const float2 r0 = ((const float2*)rot)[lane];
    const float2 r1 = ((const float2*)rot)[64 + lane];
    const float2 qq = ((const float2*)qjl)[lane];
    f2 rs0; rs0.x = r0.x; rs0.y = r0.y;
    f2 rs1; rs1.x = r1.x; rs1.y = r1.y;
    f2 qj;  qj.x  = qq.x; qj.y  = qq.y;

    const int half    = nrows >> 1;
    const int row0    = blockIdx.x * 4 + wid;
    const int wstride = gridDim.x * 4;

    const bool m1 = mode1_ok(lane, L);
    const bool m2 = m1 && mode2_ok(lane, L);
    if (m2)
        run2<2>(x, out, tbl4, rs0, rs1, qj, S, L, lane, row0, wstride, half);
    else if (m1)
        run2<1>(x, out, tbl4, rs0, rs1, qj, S, L, lane, row0, wstride, half);
    else
        run2<0>(x, out, tbl4, rs0, rs1, qj, S, L, lane, row0, wstride, half);
}

extern "C" void kernel_launch(void* const* d_in, const int* in_sizes, int n_in,
                              void* d_out, int out_size, void* d_ws, size_t ws_size,
                              hipStream_t stream) {
    const float* x   = (const float*)d_in[0];
    const float* rot = (const float*)d_in[1];
    const float* qjl = (const float*)d_in[2];
    float* out = (float*)d_out;
    float* ws  = (float*)d_ws;

    const int nrows = in_sizes[0] >> 7;

    lloyd_setup_kernel<<<1, 128, 0, stream>>>(ws);
    turboquant_kernel<<<8192, 256, 0, stream>>>(x, rot, qjl, ws, out, nrows);
}